// Round 2
// baseline (327.166 us; speedup 1.0000x reference)
//
#include <hip/hip_runtime.h>
#include <hip/hip_bf16.h>
#include <hip/hip_fp16.h>

// NNConv R15: exact-CSR compact msg. R14 post-mortem: all execution metrics
// improved (occ 36->48, bankconf 2.55M->0.4M) yet edge_k slowed 80.7->86.2 --
// counters show +70MB/dispatch HBM traffic (FETCH 57.5->82.2: blob evicted by
// 205MB slab churn; WRITE 75.6->119.4: partial 64B-row line amplification).
// Also ~70us of total is unaccounted => consistent with harness ws reset over
// 205MB. Fix both with one lever: exact CSR (deg count folded into setup grid,
// single-block scan -> off[]/cur[]), slot = atomicAdd(&cur[dst],1), msg dense
// 51.2MB. Gather sweeps msg linearly. Edge back to 256-tpb (R14's 8-wave
// barrier convoy hurt; 4 blk/CU better), keeping blob-stage + b128 h-reads.
// ws: blob 20KB | deg | off | cur | msg = 51.8MB total (was 205MB).

#define N_NODES 50000
#define N_EDGES 800000
#define IN_D    16
#define OUT_D   16
#define HID_D   32
#define KTILES  17
#define NBLK_E  (N_EDGES / 256)            // 3125, exact
#define NBLK_G  (N_NODES * OUT_D / 256)    // 3125, exact
#define BLOB_BYTES 20480                   // 20 x 1KB chunks
#define BLOB_W1    17408                   // s_B image [0,17408)
#define BLOB_B1    19456                   // w1 [17408,19456), b1 [19456,19584)

// ws layout (byte offsets)
#define WS_DEG  20480                      // 50000 ints
#define WS_OFF  220480                     // 50001 ints (padded to 200064B)
#define WS_CUR  420544                     // 50000 ints
#define WS_MSG  620544                     // E*16 f32 = 51.2MB, 16B-aligned
#define WS_NEED (620544 + (size_t)N_EDGES * 16 * 4)

typedef __attribute__((ext_vector_type(8))) _Float16 hfrag8;
typedef __attribute__((ext_vector_type(4))) float f32x4;

__device__ __forceinline__ void fma4(float a, const float4 w, float4& m) {
    m.x = fmaf(a, w.x, m.x);
    m.y = fmaf(a, w.y, m.y);
    m.z = fmaf(a, w.z, m.z);
    m.w = fmaf(a, w.w, m.w);
}
__device__ __forceinline__ int clampn(int v) {
    return v < 0 ? 0 : (v >= N_NODES ? N_NODES - 1 : v);
}
__device__ __forceinline__ void gload_lds16(const void* g, void* l) {
    __builtin_amdgcn_global_load_lds(
        (const __attribute__((address_space(1))) unsigned int*)g,
        (__attribute__((address_space(3))) unsigned int*)l,
        16, 0, 0);
}

// ---------------- setup + degree count in one grid ----------------
// block 0: build {s_B f16 image, w1, b1} blob. blocks 1..3125: count degrees.

__global__ __launch_bounds__(256) void setup_count_k(
    const float* __restrict__ w1,
    const float* __restrict__ b1,
    const float* __restrict__ w2,
    const float* __restrict__ b2,
    const int*   __restrict__ ei,
    unsigned char* __restrict__ blob,
    int* __restrict__ deg)
{
    const int t = threadIdx.x;
    if (blockIdx.x != 0) {
        const int e = (blockIdx.x - 1) * 256 + t;          // covers E exactly
        atomicAdd(&deg[clampn(ei[N_EDGES + e])], 1);
        return;
    }
    __half* bp = reinterpret_cast<__half*>(blob);
    for (int r = t; r < KTILES * 32; r += 256) {
        const int tile = r >> 5, q = (r >> 3) & 3, j = r & 7;
        const int base = ((tile * 4 + q) * 16) * 8 + j;
        float vals[16];
        if (r < 512) {
            const float4* wr = reinterpret_cast<const float4*>(w2) + r * 4;
            float4 v0 = wr[0], v1 = wr[1], v2 = wr[2], v3 = wr[3];
            vals[0]=v0.x; vals[1]=v0.y; vals[2]=v0.z; vals[3]=v0.w;
            vals[4]=v1.x; vals[5]=v1.y; vals[6]=v1.z; vals[7]=v1.w;
            vals[8]=v2.x; vals[9]=v2.y; vals[10]=v2.z; vals[11]=v2.w;
            vals[12]=v3.x; vals[13]=v3.y; vals[14]=v3.z; vals[15]=v3.w;
        } else if (r < 528) {
            const float4* br = reinterpret_cast<const float4*>(b2) + (r - 512) * 4;
            float4 v0 = br[0], v1 = br[1], v2 = br[2], v3 = br[3];
            vals[0]=v0.x; vals[1]=v0.y; vals[2]=v0.z; vals[3]=v0.w;
            vals[4]=v1.x; vals[5]=v1.y; vals[6]=v1.z; vals[7]=v1.w;
            vals[8]=v2.x; vals[9]=v2.y; vals[10]=v2.z; vals[11]=v2.w;
            vals[12]=v3.x; vals[13]=v3.y; vals[14]=v3.z; vals[15]=v3.w;
        } else {
            #pragma unroll
            for (int o = 0; o < 16; ++o) vals[o] = 0.f;
        }
        #pragma unroll
        for (int o = 0; o < 16; ++o) bp[base + o * 8] = __float2half(vals[o]);
    }
    float* wf = reinterpret_cast<float*>(blob + BLOB_W1);
    wf[t]       = w1[t];
    wf[t + 256] = w1[t + 256];
    if (t < HID_D) reinterpret_cast<float*>(blob + BLOB_B1)[t] = b1[t];
}

// ---------------- single-block exclusive scan: off[] and cur[] ----------------

__global__ __launch_bounds__(1024) void scan_k(
    const int* __restrict__ deg,
    int* __restrict__ off,
    int* __restrict__ cur)
{
    __shared__ int s[1024];
    const int t = threadIdx.x;
    const int CH = 49;                       // 1024*49 = 50176 >= 50000
    const int base = t * CH;

    int tot = 0;
    for (int i = 0; i < CH; ++i) {
        const int n = base + i;
        if (n < N_NODES) tot += deg[n];
    }
    s[t] = tot;
    __syncthreads();
    for (int d = 1; d < 1024; d <<= 1) {     // Hillis-Steele inclusive scan
        const int v   = s[t];
        const int add = (t >= d) ? s[t - d] : 0;
        __syncthreads();
        s[t] = v + add;
        __syncthreads();
    }
    int run = (t == 0) ? 0 : s[t - 1];       // exclusive prefix
    for (int i = 0; i < CH; ++i) {
        const int n = base + i;
        if (n < N_NODES) {
            off[n] = run;
            cur[n] = run;
            run += deg[n];
        }
    }
    if (t == 1023) off[N_NODES] = run;       // = N_EDGES
}

// ---------------- edge kernel: 256 threads, blob staging, b128 h-reads ----------------
// MODE: 0 = CSR (aux = cur cursors), 1 = linked-list (aux = head4, next)

template <int MODE>
__global__ __launch_bounds__(256) void edge_k(
    const float* __restrict__ x,
    const int*   __restrict__ ei,
    const float* __restrict__ ea,
    const unsigned char* __restrict__ gblob,
    int*   __restrict__ aux,
    int*   __restrict__ next,
    float* __restrict__ msg)
{
    __shared__ alignas(16) unsigned char s_blob[BLOB_BYTES];   // 20 KB
    __shared__ alignas(16) __half s_h2[4 * 64 * 32];           // 16 KB: [wave][edge 64B row]

    const int t    = threadIdx.x;
    const int lane = t & 63;
    const int w    = t >> 6;
    const int e    = blockIdx.x * 256 + t;   // grid exact

    // ---- blob global->LDS: 20 x 1KB chunks across 4 waves
    #pragma unroll
    for (int j = 0; j < 5; ++j) {
        const int ch = w + 4 * j;            // 0..19
        gload_lds16(gblob + ch * 1024 + lane * 16, s_blob + ch * 1024);
    }

    const hfrag8* s_B  = reinterpret_cast<const hfrag8*>(s_blob);
    const float4* s_w1 = reinterpret_cast<const float4*>(s_blob + BLOB_W1);
    const float4* s_b1 = reinterpret_cast<const float4*>(s_blob + BLOB_B1);

    const int q   = lane >> 4;
    const int n   = lane & 15;
    const int qh  = q >> 1;
    const int i0q = (q & 1) * 8;

    // ---- indices + slot, x/ea prefetch before the barrier ----
    const int src = clampn(ei[e]);
    const int dst = clampn(ei[N_EDGES + e]);
    int slot;
    if (MODE == 0) {
        slot = atomicAdd(&aux[dst], 1);      // exact capacity: rank < deg[dst]
    } else {
        next[e] = atomicExch(&aux[dst * 4 + (e & 3)], e);
        slot = e;
    }
    float4 xpre[4][2];
    #pragma unroll
    for (int sub = 0; sub < 4; ++sub) {
        const int srcB = __shfl(src, sub * 16 + n, 64);
        const float4* xp = reinterpret_cast<const float4*>(x) + (size_t)srcB * 4 + (i0q >> 2);
        xpre[sub][0] = xp[0];
        xpre[sub][1] = xp[1];
    }
    float eav[IN_D];
    {
        const float4* eap = reinterpret_cast<const float4*>(ea) + (size_t)e * 4;
        float4 a0 = eap[0], a1 = eap[1], a2 = eap[2], a3 = eap[3];
        eav[0]=a0.x;  eav[1]=a0.y;  eav[2]=a0.z;  eav[3]=a0.w;
        eav[4]=a1.x;  eav[5]=a1.y;  eav[6]=a1.z;  eav[7]=a1.w;
        eav[8]=a2.x;  eav[9]=a2.y;  eav[10]=a2.z; eav[11]=a2.w;
        eav[12]=a3.x; eav[13]=a3.y; eav[14]=a3.z; eav[15]=a3.w;
    }

    __syncthreads();            // drains vmcnt (global_load_lds) + makes blob visible

    // ---- edge MLP h = relu(ea@w1+b1) -> packed 64B row, swizzled b128 writes ----
    {
        float4 hv[HID_D / 4];
        #pragma unroll
        for (int j = 0; j < HID_D / 4; ++j) hv[j] = s_b1[j];
        #pragma unroll
        for (int i = 0; i < IN_D; ++i) {
            const float xi = eav[i];
            #pragma unroll
            for (int j = 0; j < HID_D / 4; ++j) fma4(xi, s_w1[i * (HID_D / 4) + j], hv[j]);
        }
        // logical row layout: h[k] at slot (k&1)*16 + (k>>1)
        union { hfrag8 v[4]; __half h[32]; } hp;
        #pragma unroll
        for (int jj = 0; jj < 8; ++jj) {
            const int k0 = 4 * jj;
            hp.h[((k0 + 0) & 1) * 16 + ((k0 + 0) >> 1)] = __float2half(fmaxf(hv[jj].x, 0.f));
            hp.h[((k0 + 1) & 1) * 16 + ((k0 + 1) >> 1)] = __float2half(fmaxf(hv[jj].y, 0.f));
            hp.h[((k0 + 2) & 1) * 16 + ((k0 + 2) >> 1)] = __float2half(fmaxf(hv[jj].z, 0.f));
            hp.h[((k0 + 3) & 1) * 16 + ((k0 + 3) >> 1)] = __float2half(fmaxf(hv[jj].w, 0.f));
        }
        hfrag8* rowv = reinterpret_cast<hfrag8*>(s_h2 + (size_t)w * 2048 + lane * 32);
        const int swl = (lane >> 1) & 3;          // 16B-chunk XOR swizzle
        rowv[0 ^ swl] = hp.v[0];
        rowv[1 ^ swl] = hp.v[1];
        rowv[2 ^ swl] = hp.v[2];
        rowv[3 ^ swl] = hp.v[3];
    }
    asm volatile("s_waitcnt lgkmcnt(0)" ::: "memory");
    __builtin_amdgcn_wave_barrier();

    // ---- MFMA phase: 2x ds_read_b128 per sub replaces 17x ds_read_u16 ----
    const __half* hbase = s_h2 + (size_t)w * 2048;
    #pragma unroll
    for (int sub = 0; sub < 4; ++sub) {
        const int posW = sub * 16 + n;
        __half2 xh[4];
        {
            float4 xa = xpre[sub][0], xb = xpre[sub][1];
            xh[0] = __float22half2_rn(make_float2(xa.x, xa.y));
            xh[1] = __float22half2_rn(make_float2(xa.z, xa.w));
            xh[2] = __float22half2_rn(make_float2(xb.x, xb.y));
            xh[3] = __float22half2_rn(make_float2(xb.z, xb.w));
        }
        union { hfrag8 v; __half h[8]; } hA, hB;   // tiles 0-7 / 8-15 for this qh
        {
            const hfrag8* rowv = reinterpret_cast<const hfrag8*>(hbase + posW * 32);
            const int swr = (posW >> 1) & 3;
            hA.v = rowv[(2 * qh + 0) ^ swr];
            hB.v = rowv[(2 * qh + 1) ^ swr];
        }
        f32x4 acc = {0.f, 0.f, 0.f, 0.f};
        #pragma unroll
        for (int tile = 0; tile < 16; ++tile) {
            const __half hs = (tile < 8) ? hA.h[tile] : hB.h[tile - 8];   // h[2*tile+qh]
            const __half2 hh = __half2half2(hs);
            union { hfrag8 v; __half2 h[4]; } a;
            a.h[0] = __hmul2(hh, xh[0]);
            a.h[1] = __hmul2(hh, xh[1]);
            a.h[2] = __hmul2(hh, xh[2]);
            a.h[3] = __hmul2(hh, xh[3]);
            acc = __builtin_amdgcn_mfma_f32_16x16x32_f16(a.v, s_B[tile * 64 + lane], acc, 0, 0, 0);
        }
        {   // b2 tile: A = x (qh==0) / 0 (qh==1)
            union { hfrag8 v; __half2 h[4]; } a;
            if (qh == 0) { a.h[0]=xh[0]; a.h[1]=xh[1]; a.h[2]=xh[2]; a.h[3]=xh[3]; }
            else { hfrag8 z = {0,0,0,0,0,0,0,0}; a.v = z; }
            acc = __builtin_amdgcn_mfma_f32_16x16x32_f16(a.v, s_B[16 * 64 + lane], acc, 0, 0, 0);
        }
        #pragma unroll
        for (int r = 0; r < 4; ++r) {
            const int slotB = __shfl(slot, sub * 16 + q * 4 + r, 64);
            msg[(size_t)slotB * 16 + n] = acc[r];
        }
    }
}

// ---------------- CSR gather: linear sweep of compact msg ----------------

__global__ __launch_bounds__(256) void gather_csr(
    const float* __restrict__ x,
    const float* __restrict__ root,
    const float* __restrict__ bias,
    const float* __restrict__ msg,
    const int*   __restrict__ off,
    float* __restrict__ out)
{
    __shared__ float4 s_root4[IN_D * 4];
    __shared__ float4 s_bias4[4];
    const int t = threadIdx.x;
    if (t < IN_D * 4) s_root4[t] = reinterpret_cast<const float4*>(root)[t];
    if (t < 4)        s_bias4[t] = reinterpret_cast<const float4*>(bias)[t];
    __syncthreads();

    const int g = blockIdx.x * 256 + t;      // grid exact: 3125*256 = 50000*16
    const int n = g >> 4;
    const int l = t & 15;
    const int c = l >> 2;                    // row-chain 0..3
    const int p = l & 3;                     // float4 column 0..3

    const int s0 = off[n];
    const int d  = off[n + 1] - s0;

    const float4* base = reinterpret_cast<const float4*>(msg) + (size_t)s0 * 4 + p;
    float4 a0 = make_float4(0.f, 0.f, 0.f, 0.f);
    float4 a1 = make_float4(0.f, 0.f, 0.f, 0.f);
    int j = c;
    for (; j + 4 < d; j += 8) {              // 2 rows/lane/iter -> 8 rows in flight per group
        float4 v0 = base[(size_t)j * 4];
        float4 v1 = base[(size_t)(j + 4) * 4];
        a0.x += v0.x; a0.y += v0.y; a0.z += v0.z; a0.w += v0.w;
        a1.x += v1.x; a1.y += v1.y; a1.z += v1.z; a1.w += v1.w;
    }
    if (j < d) {
        float4 v0 = base[(size_t)j * 4];
        a0.x += v0.x; a0.y += v0.y; a0.z += v0.z; a0.w += v0.w;
    }
    float4 acc = make_float4(a0.x + a1.x, a0.y + a1.y, a0.z + a1.z, a0.w + a1.w);

    acc.x += __shfl_xor(acc.x, 4); acc.y += __shfl_xor(acc.y, 4);
    acc.z += __shfl_xor(acc.z, 4); acc.w += __shfl_xor(acc.w, 4);
    acc.x += __shfl_xor(acc.x, 8); acc.y += __shfl_xor(acc.y, 8);
    acc.z += __shfl_xor(acc.z, 8); acc.w += __shfl_xor(acc.w, 8);

    const float inv = 1.0f / (float)(d > 1 ? d : 1);
    float4 mv = s_bias4[p];
    mv.x += acc.x * inv; mv.y += acc.y * inv; mv.z += acc.z * inv; mv.w += acc.w * inv;

    {
        const float4* xp = reinterpret_cast<const float4*>(x) + (size_t)n * 4;
        float4 x0 = xp[0], x1 = xp[1], x2 = xp[2], x3 = xp[3];
        const float xs[IN_D] = { x0.x,x0.y,x0.z,x0.w, x1.x,x1.y,x1.z,x1.w,
                                 x2.x,x2.y,x2.z,x2.w, x3.x,x3.y,x3.z,x3.w };
        #pragma unroll
        for (int i = 0; i < IN_D; ++i) fma4(xs[i], s_root4[i * 4 + p], mv);
    }

    if (c == 0)
        reinterpret_cast<float4*>(out + (size_t)n * 16)[p] = mv;
}

// ---------------- linked-list gather (fallback) ----------------

__global__ __launch_bounds__(256) void gather_ll4(
    const float* __restrict__ x,
    const float* __restrict__ root,
    const float* __restrict__ bias,
    const float* __restrict__ msg,
    const int*   __restrict__ head4,
    const int*   __restrict__ next,
    float* __restrict__ out)
{
    __shared__ float4 s_root4[IN_D * 4];
    __shared__ float4 s_bias4[4];
    const int t = threadIdx.x;
    if (t < IN_D * 4) s_root4[t] = reinterpret_cast<const float4*>(root)[t];
    if (t < 4)        s_bias4[t] = reinterpret_cast<const float4*>(bias)[t];
    __syncthreads();

    const int g = blockIdx.x * 256 + t;
    const int n = g >> 4;
    const int l = t & 15;
    const int c = l >> 2;
    const int p = l & 3;

    float4 acc = make_float4(0.f, 0.f, 0.f, 0.f);
    int cnt = 0;
    int j = head4[n * 4 + c];                // poison 0xAAAAAAAA < 0 = empty
    while (j >= 0) {
        const float4 v = reinterpret_cast<const float4*>(msg + (size_t)j * 16)[p];
        acc.x += v.x; acc.y += v.y; acc.z += v.z; acc.w += v.w;
        ++cnt;
        j = next[j];
    }

    acc.x += __shfl_xor(acc.x, 4); acc.y += __shfl_xor(acc.y, 4);
    acc.z += __shfl_xor(acc.z, 4); acc.w += __shfl_xor(acc.w, 4);
    cnt   += __shfl_xor(cnt, 4);
    acc.x += __shfl_xor(acc.x, 8); acc.y += __shfl_xor(acc.y, 8);
    acc.z += __shfl_xor(acc.z, 8); acc.w += __shfl_xor(acc.w, 8);
    cnt   += __shfl_xor(cnt, 8);

    const float inv = 1.0f / (float)(cnt > 1 ? cnt : 1);
    float4 m = s_bias4[p];
    m.x += acc.x * inv; m.y += acc.y * inv; m.z += acc.z * inv; m.w += acc.w * inv;

    {
        const float4* xp = reinterpret_cast<const float4*>(x) + (size_t)n * 4;
        float4 x0 = xp[0], x1 = xp[1], x2 = xp[2], x3 = xp[3];
        const float xs[IN_D] = { x0.x,x0.y,x0.z,x0.w, x1.x,x1.y,x1.z,x1.w,
                                 x2.x,x2.y,x2.z,x2.w, x3.x,x3.y,x3.z,x3.w };
        #pragma unroll
        for (int i = 0; i < IN_D; ++i) fma4(xs[i], s_root4[i * 4 + p], m);
    }

    if (c == 0)
        reinterpret_cast<float4*>(out + (size_t)n * 16)[p] = m;
}

extern "C" void kernel_launch(void* const* d_in, const int* in_sizes, int n_in,
                              void* d_out, int out_size, void* d_ws, size_t ws_size,
                              hipStream_t stream) {
    const float* x    = (const float*)d_in[0];
    const int*   ei   = (const int*)  d_in[1];
    const float* ea   = (const float*)d_in[2];
    const float* w1   = (const float*)d_in[3];
    const float* b1   = (const float*)d_in[4];
    const float* w2   = (const float*)d_in[5];
    const float* b2   = (const float*)d_in[6];
    const float* root = (const float*)d_in[7];
    const float* bias = (const float*)d_in[8];
    float* out = (float*)d_out;

    unsigned char* ws = (unsigned char*)d_ws;
    unsigned char* blob = ws;

    if (ws_size >= WS_NEED) {
        int*   deg = (int*)(ws + WS_DEG);
        int*   off = (int*)(ws + WS_OFF);
        int*   cur = (int*)(ws + WS_CUR);
        float* msg = (float*)(ws + WS_MSG);
        hipMemsetAsync(deg, 0, N_NODES * sizeof(int), stream);
        setup_count_k<<<NBLK_E + 1, 256, 0, stream>>>(w1, b1, w2, b2, ei, blob, deg);
        scan_k<<<1, 1024, 0, stream>>>(deg, off, cur);
        edge_k<0><<<NBLK_E, 256, 0, stream>>>(x, ei, ea, blob, cur, nullptr, msg);
        gather_csr<<<NBLK_G, 256, 0, stream>>>(x, root, bias, msg, off, out);
    } else {
        // 4-way linked list fallback (requires 0xAA ws poison for head4 sentinel)
        int*   head4 = (int*)(ws + BLOB_BYTES);       // N*4 ints
        int*   next  = head4 + N_NODES * 4;           // E ints
        float* msg   = (float*)(next + N_EDGES);      // E*16 f32
        setup_count_k<<<1, 256, 0, stream>>>(w1, b1, w2, b2, ei, blob, (int*)(ws + BLOB_BYTES)); // block0 only builds blob; deg unused
        edge_k<1><<<NBLK_E, 256, 0, stream>>>(x, ei, ea, blob, head4, next, msg);
        gather_ll4  <<<NBLK_G, 256, 0, stream>>>(x, root, bias, msg, head4, next, out);
    }
}

// Round 3
// 209.355 us; speedup vs baseline: 1.5627x; 1.5627x over previous
//
#include <hip/hip_runtime.h>
#include <hip/hip_bf16.h>
#include <hip/hip_fp16.h>

// NNConv R16: R15's exact-CSR plan with the scan done right. R15 post-mortem:
// scan_k (single block, 1024 thr) = 127us, 0.1% occupancy, 4 GB/s -- one CU
// serializing the pipeline. Replaced with hierarchical parallel scan:
//   scan1_k : 196 blk x 256 -- block sum of deg -> bsum[196]     (~3us)
//   scan23_k: 196 blk x 256 -- LDS scan of bsum (redundant per block) + in-
//             block scan of deg -> off[]/cur[], off[N]=E          (~4us)
// Edge/gather unchanged from R15 (256tpb, blob global_load_lds staging,
// swizzled b128 h-reads, compact 51.2MB msg, linear gather sweep) so this
// round isolates the scan fix and yields readable edge/gather counters.
// ws: blob 20KB | deg | off | cur | bsum | msg  = 51.8MB.

#define N_NODES 50000
#define N_EDGES 800000
#define IN_D    16
#define OUT_D   16
#define HID_D   32
#define KTILES  17
#define NBLK_E  (N_EDGES / 256)            // 3125, exact
#define NBLK_G  (N_NODES * OUT_D / 256)    // 3125, exact
#define NBLK_S  ((N_NODES + 255) / 256)    // 196
#define BLOB_BYTES 20480                   // 20 x 1KB chunks
#define BLOB_W1    17408                   // s_B image [0,17408)
#define BLOB_B1    19456                   // w1 [17408,19456), b1 [19456,19584)

// ws layout (byte offsets)
#define WS_DEG   20480                     // 50000 ints
#define WS_OFF   220480                    // 50001 ints (pad to 200064B)
#define WS_CUR   420544                    // 50000 ints
#define WS_BSUM  620544                    // 196 ints (pad to 1024B)
#define WS_MSG   621568                    // E*16 f32 = 51.2MB, 16B-aligned
#define WS_NEED  (621568 + (size_t)N_EDGES * 16 * 4)

typedef __attribute__((ext_vector_type(8))) _Float16 hfrag8;
typedef __attribute__((ext_vector_type(4))) float f32x4;

__device__ __forceinline__ void fma4(float a, const float4 w, float4& m) {
    m.x = fmaf(a, w.x, m.x);
    m.y = fmaf(a, w.y, m.y);
    m.z = fmaf(a, w.z, m.z);
    m.w = fmaf(a, w.w, m.w);
}
__device__ __forceinline__ int clampn(int v) {
    return v < 0 ? 0 : (v >= N_NODES ? N_NODES - 1 : v);
}
__device__ __forceinline__ void gload_lds16(const void* g, void* l) {
    __builtin_amdgcn_global_load_lds(
        (const __attribute__((address_space(1))) unsigned int*)g,
        (__attribute__((address_space(3))) unsigned int*)l,
        16, 0, 0);
}

// ---------------- setup + degree count in one grid ----------------
// block 0: build {s_B f16 image, w1, b1} blob. blocks 1..3125: count degrees.

__global__ __launch_bounds__(256) void setup_count_k(
    const float* __restrict__ w1,
    const float* __restrict__ b1,
    const float* __restrict__ w2,
    const float* __restrict__ b2,
    const int*   __restrict__ ei,
    unsigned char* __restrict__ blob,
    int* __restrict__ deg)
{
    const int t = threadIdx.x;
    if (blockIdx.x != 0) {
        const int e = (blockIdx.x - 1) * 256 + t;          // covers E exactly
        atomicAdd(&deg[clampn(ei[N_EDGES + e])], 1);
        return;
    }
    __half* bp = reinterpret_cast<__half*>(blob);
    for (int r = t; r < KTILES * 32; r += 256) {
        const int tile = r >> 5, q = (r >> 3) & 3, j = r & 7;
        const int base = ((tile * 4 + q) * 16) * 8 + j;
        float vals[16];
        if (r < 512) {
            const float4* wr = reinterpret_cast<const float4*>(w2) + r * 4;
            float4 v0 = wr[0], v1 = wr[1], v2 = wr[2], v3 = wr[3];
            vals[0]=v0.x; vals[1]=v0.y; vals[2]=v0.z; vals[3]=v0.w;
            vals[4]=v1.x; vals[5]=v1.y; vals[6]=v1.z; vals[7]=v1.w;
            vals[8]=v2.x; vals[9]=v2.y; vals[10]=v2.z; vals[11]=v2.w;
            vals[12]=v3.x; vals[13]=v3.y; vals[14]=v3.z; vals[15]=v3.w;
        } else if (r < 528) {
            const float4* br = reinterpret_cast<const float4*>(b2) + (r - 512) * 4;
            float4 v0 = br[0], v1 = br[1], v2 = br[2], v3 = br[3];
            vals[0]=v0.x; vals[1]=v0.y; vals[2]=v0.z; vals[3]=v0.w;
            vals[4]=v1.x; vals[5]=v1.y; vals[6]=v1.z; vals[7]=v1.w;
            vals[8]=v2.x; vals[9]=v2.y; vals[10]=v2.z; vals[11]=v2.w;
            vals[12]=v3.x; vals[13]=v3.y; vals[14]=v3.z; vals[15]=v3.w;
        } else {
            #pragma unroll
            for (int o = 0; o < 16; ++o) vals[o] = 0.f;
        }
        #pragma unroll
        for (int o = 0; o < 16; ++o) bp[base + o * 8] = __float2half(vals[o]);
    }
    float* wf = reinterpret_cast<float*>(blob + BLOB_W1);
    wf[t]       = w1[t];
    wf[t + 256] = w1[t + 256];
    if (t < HID_D) reinterpret_cast<float*>(blob + BLOB_B1)[t] = b1[t];
}

// ---------------- parallel scan, stage 1: per-block sums ----------------

__global__ __launch_bounds__(256) void scan1_k(
    const int* __restrict__ deg,
    int* __restrict__ bsum)
{
    const int t = threadIdx.x;
    const int n = blockIdx.x * 256 + t;
    int v = (n < N_NODES) ? deg[n] : 0;
    #pragma unroll
    for (int o = 1; o < 64; o <<= 1) v += __shfl_xor(v, o);
    __shared__ int sw[4];
    if ((t & 63) == 0) sw[t >> 6] = v;
    __syncthreads();
    if (t == 0) bsum[blockIdx.x] = sw[0] + sw[1] + sw[2] + sw[3];
}

// ---------------- parallel scan, stage 2: offsets + cursors ----------------
// Each block redundantly scans bsum[196] in LDS (cheap), then scans its own
// 256 deg values and writes off/cur. Last node also writes off[N]=E.

__global__ __launch_bounds__(256) void scan23_k(
    const int* __restrict__ deg,
    const int* __restrict__ bsum,
    int* __restrict__ off,
    int* __restrict__ cur)
{
    __shared__ int sb[256];
    __shared__ int sd[256];
    const int t = threadIdx.x;
    const int b = blockIdx.x;

    sb[t] = (t < NBLK_S) ? bsum[t] : 0;
    const int n  = b * 256 + t;
    const int dn = (n < N_NODES) ? deg[n] : 0;
    sd[t] = dn;
    __syncthreads();

    #pragma unroll
    for (int d = 1; d < 256; d <<= 1) {      // Hillis-Steele inclusive, both arrays
        const int vb = sb[t], va = sd[t];
        const int ab = (t >= d) ? sb[t - d] : 0;
        const int aa = (t >= d) ? sd[t - d] : 0;
        __syncthreads();
        sb[t] = vb + ab;
        sd[t] = va + aa;
        __syncthreads();
    }

    const int base = (b == 0) ? 0 : sb[b - 1];       // exclusive prefix of blocks
    const int p    = base + sd[t] - dn;              // exclusive prefix of nodes
    if (n < N_NODES) {
        off[n] = p;
        cur[n] = p;
        if (n == N_NODES - 1) off[N_NODES] = p + dn; // = N_EDGES
    }
}

// ---------------- edge kernel: 256 threads, blob staging, b128 h-reads ----------------
// MODE: 0 = CSR (aux = cur cursors), 1 = linked-list (aux = head4, next)

template <int MODE>
__global__ __launch_bounds__(256) void edge_k(
    const float* __restrict__ x,
    const int*   __restrict__ ei,
    const float* __restrict__ ea,
    const unsigned char* __restrict__ gblob,
    int*   __restrict__ aux,
    int*   __restrict__ next,
    float* __restrict__ msg)
{
    __shared__ alignas(16) unsigned char s_blob[BLOB_BYTES];   // 20 KB
    __shared__ alignas(16) __half s_h2[4 * 64 * 32];           // 16 KB: [wave][edge 64B row]

    const int t    = threadIdx.x;
    const int lane = t & 63;
    const int w    = t >> 6;
    const int e    = blockIdx.x * 256 + t;   // grid exact

    // ---- blob global->LDS: 20 x 1KB chunks across 4 waves
    #pragma unroll
    for (int j = 0; j < 5; ++j) {
        const int ch = w + 4 * j;            // 0..19
        gload_lds16(gblob + ch * 1024 + lane * 16, s_blob + ch * 1024);
    }

    const hfrag8* s_B  = reinterpret_cast<const hfrag8*>(s_blob);
    const float4* s_w1 = reinterpret_cast<const float4*>(s_blob + BLOB_W1);
    const float4* s_b1 = reinterpret_cast<const float4*>(s_blob + BLOB_B1);

    const int q   = lane >> 4;
    const int n   = lane & 15;
    const int qh  = q >> 1;
    const int i0q = (q & 1) * 8;

    // ---- indices + slot, x/ea prefetch before the barrier ----
    const int src = clampn(ei[e]);
    const int dst = clampn(ei[N_EDGES + e]);
    int slot;
    if (MODE == 0) {
        slot = atomicAdd(&aux[dst], 1);      // exact capacity: rank < deg[dst]
    } else {
        next[e] = atomicExch(&aux[dst * 4 + (e & 3)], e);
        slot = e;
    }
    float4 xpre[4][2];
    #pragma unroll
    for (int sub = 0; sub < 4; ++sub) {
        const int srcB = __shfl(src, sub * 16 + n, 64);
        const float4* xp = reinterpret_cast<const float4*>(x) + (size_t)srcB * 4 + (i0q >> 2);
        xpre[sub][0] = xp[0];
        xpre[sub][1] = xp[1];
    }
    float eav[IN_D];
    {
        const float4* eap = reinterpret_cast<const float4*>(ea) + (size_t)e * 4;
        float4 a0 = eap[0], a1 = eap[1], a2 = eap[2], a3 = eap[3];
        eav[0]=a0.x;  eav[1]=a0.y;  eav[2]=a0.z;  eav[3]=a0.w;
        eav[4]=a1.x;  eav[5]=a1.y;  eav[6]=a1.z;  eav[7]=a1.w;
        eav[8]=a2.x;  eav[9]=a2.y;  eav[10]=a2.z; eav[11]=a2.w;
        eav[12]=a3.x; eav[13]=a3.y; eav[14]=a3.z; eav[15]=a3.w;
    }

    __syncthreads();            // drains vmcnt (global_load_lds) + makes blob visible

    // ---- edge MLP h = relu(ea@w1+b1) -> packed 64B row, swizzled b128 writes ----
    {
        float4 hv[HID_D / 4];
        #pragma unroll
        for (int j = 0; j < HID_D / 4; ++j) hv[j] = s_b1[j];
        #pragma unroll
        for (int i = 0; i < IN_D; ++i) {
            const float xi = eav[i];
            #pragma unroll
            for (int j = 0; j < HID_D / 4; ++j) fma4(xi, s_w1[i * (HID_D / 4) + j], hv[j]);
        }
        // logical row layout: h[k] at slot (k&1)*16 + (k>>1)
        union { hfrag8 v[4]; __half h[32]; } hp;
        #pragma unroll
        for (int jj = 0; jj < 8; ++jj) {
            const int k0 = 4 * jj;
            hp.h[((k0 + 0) & 1) * 16 + ((k0 + 0) >> 1)] = __float2half(fmaxf(hv[jj].x, 0.f));
            hp.h[((k0 + 1) & 1) * 16 + ((k0 + 1) >> 1)] = __float2half(fmaxf(hv[jj].y, 0.f));
            hp.h[((k0 + 2) & 1) * 16 + ((k0 + 2) >> 1)] = __float2half(fmaxf(hv[jj].z, 0.f));
            hp.h[((k0 + 3) & 1) * 16 + ((k0 + 3) >> 1)] = __float2half(fmaxf(hv[jj].w, 0.f));
        }
        hfrag8* rowv = reinterpret_cast<hfrag8*>(s_h2 + (size_t)w * 2048 + lane * 32);
        const int swl = (lane >> 1) & 3;          // 16B-chunk XOR swizzle
        rowv[0 ^ swl] = hp.v[0];
        rowv[1 ^ swl] = hp.v[1];
        rowv[2 ^ swl] = hp.v[2];
        rowv[3 ^ swl] = hp.v[3];
    }
    asm volatile("s_waitcnt lgkmcnt(0)" ::: "memory");
    __builtin_amdgcn_wave_barrier();

    // ---- MFMA phase: 2x ds_read_b128 per sub replaces 17x ds_read_u16 ----
    const __half* hbase = s_h2 + (size_t)w * 2048;
    #pragma unroll
    for (int sub = 0; sub < 4; ++sub) {
        const int posW = sub * 16 + n;
        __half2 xh[4];
        {
            float4 xa = xpre[sub][0], xb = xpre[sub][1];
            xh[0] = __float22half2_rn(make_float2(xa.x, xa.y));
            xh[1] = __float22half2_rn(make_float2(xa.z, xa.w));
            xh[2] = __float22half2_rn(make_float2(xb.x, xb.y));
            xh[3] = __float22half2_rn(make_float2(xb.z, xb.w));
        }
        union { hfrag8 v; __half h[8]; } hA, hB;   // tiles 0-7 / 8-15 for this qh
        {
            const hfrag8* rowv = reinterpret_cast<const hfrag8*>(hbase + posW * 32);
            const int swr = (posW >> 1) & 3;
            hA.v = rowv[(2 * qh + 0) ^ swr];
            hB.v = rowv[(2 * qh + 1) ^ swr];
        }
        f32x4 acc = {0.f, 0.f, 0.f, 0.f};
        #pragma unroll
        for (int tile = 0; tile < 16; ++tile) {
            const __half hs = (tile < 8) ? hA.h[tile] : hB.h[tile - 8];   // h[2*tile+qh]
            const __half2 hh = __half2half2(hs);
            union { hfrag8 v; __half2 h[4]; } a;
            a.h[0] = __hmul2(hh, xh[0]);
            a.h[1] = __hmul2(hh, xh[1]);
            a.h[2] = __hmul2(hh, xh[2]);
            a.h[3] = __hmul2(hh, xh[3]);
            acc = __builtin_amdgcn_mfma_f32_16x16x32_f16(a.v, s_B[tile * 64 + lane], acc, 0, 0, 0);
        }
        {   // b2 tile: A = x (qh==0) / 0 (qh==1)
            union { hfrag8 v; __half2 h[4]; } a;
            if (qh == 0) { a.h[0]=xh[0]; a.h[1]=xh[1]; a.h[2]=xh[2]; a.h[3]=xh[3]; }
            else { hfrag8 z = {0,0,0,0,0,0,0,0}; a.v = z; }
            acc = __builtin_amdgcn_mfma_f32_16x16x32_f16(a.v, s_B[16 * 64 + lane], acc, 0, 0, 0);
        }
        #pragma unroll
        for (int r = 0; r < 4; ++r) {
            const int slotB = __shfl(slot, sub * 16 + q * 4 + r, 64);
            msg[(size_t)slotB * 16 + n] = acc[r];
        }
    }
}

// ---------------- CSR gather: linear sweep of compact msg ----------------

__global__ __launch_bounds__(256) void gather_csr(
    const float* __restrict__ x,
    const float* __restrict__ root,
    const float* __restrict__ bias,
    const float* __restrict__ msg,
    const int*   __restrict__ off,
    float* __restrict__ out)
{
    __shared__ float4 s_root4[IN_D * 4];
    __shared__ float4 s_bias4[4];
    const int t = threadIdx.x;
    if (t < IN_D * 4) s_root4[t] = reinterpret_cast<const float4*>(root)[t];
    if (t < 4)        s_bias4[t] = reinterpret_cast<const float4*>(bias)[t];
    __syncthreads();

    const int g = blockIdx.x * 256 + t;      // grid exact: 3125*256 = 50000*16
    const int n = g >> 4;
    const int l = t & 15;
    const int c = l >> 2;                    // row-chain 0..3
    const int p = l & 3;                     // float4 column 0..3

    const int s0 = off[n];
    const int d  = off[n + 1] - s0;

    const float4* base = reinterpret_cast<const float4*>(msg) + (size_t)s0 * 4 + p;
    float4 a0 = make_float4(0.f, 0.f, 0.f, 0.f);
    float4 a1 = make_float4(0.f, 0.f, 0.f, 0.f);
    int j = c;
    for (; j + 4 < d; j += 8) {              // 2 rows/lane/iter -> 8 rows in flight per group
        float4 v0 = base[(size_t)j * 4];
        float4 v1 = base[(size_t)(j + 4) * 4];
        a0.x += v0.x; a0.y += v0.y; a0.z += v0.z; a0.w += v0.w;
        a1.x += v1.x; a1.y += v1.y; a1.z += v1.z; a1.w += v1.w;
    }
    if (j < d) {
        float4 v0 = base[(size_t)j * 4];
        a0.x += v0.x; a0.y += v0.y; a0.z += v0.z; a0.w += v0.w;
    }
    float4 acc = make_float4(a0.x + a1.x, a0.y + a1.y, a0.z + a1.z, a0.w + a1.w);

    acc.x += __shfl_xor(acc.x, 4); acc.y += __shfl_xor(acc.y, 4);
    acc.z += __shfl_xor(acc.z, 4); acc.w += __shfl_xor(acc.w, 4);
    acc.x += __shfl_xor(acc.x, 8); acc.y += __shfl_xor(acc.y, 8);
    acc.z += __shfl_xor(acc.z, 8); acc.w += __shfl_xor(acc.w, 8);

    const float inv = 1.0f / (float)(d > 1 ? d : 1);
    float4 mv = s_bias4[p];
    mv.x += acc.x * inv; mv.y += acc.y * inv; mv.z += acc.z * inv; mv.w += acc.w * inv;

    {
        const float4* xp = reinterpret_cast<const float4*>(x) + (size_t)n * 4;
        float4 x0 = xp[0], x1 = xp[1], x2 = xp[2], x3 = xp[3];
        const float xs[IN_D] = { x0.x,x0.y,x0.z,x0.w, x1.x,x1.y,x1.z,x1.w,
                                 x2.x,x2.y,x2.z,x2.w, x3.x,x3.y,x3.z,x3.w };
        #pragma unroll
        for (int i = 0; i < IN_D; ++i) fma4(xs[i], s_root4[i * 4 + p], mv);
    }

    if (c == 0)
        reinterpret_cast<float4*>(out + (size_t)n * 16)[p] = mv;
}

// ---------------- linked-list gather (fallback) ----------------

__global__ __launch_bounds__(256) void gather_ll4(
    const float* __restrict__ x,
    const float* __restrict__ root,
    const float* __restrict__ bias,
    const float* __restrict__ msg,
    const int*   __restrict__ head4,
    const int*   __restrict__ next,
    float* __restrict__ out)
{
    __shared__ float4 s_root4[IN_D * 4];
    __shared__ float4 s_bias4[4];
    const int t = threadIdx.x;
    if (t < IN_D * 4) s_root4[t] = reinterpret_cast<const float4*>(root)[t];
    if (t < 4)        s_bias4[t] = reinterpret_cast<const float4*>(bias)[t];
    __syncthreads();

    const int g = blockIdx.x * 256 + t;
    const int n = g >> 4;
    const int l = t & 15;
    const int c = l >> 2;
    const int p = l & 3;

    float4 acc = make_float4(0.f, 0.f, 0.f, 0.f);
    int cnt = 0;
    int j = head4[n * 4 + c];                // poison 0xAAAAAAAA < 0 = empty
    while (j >= 0) {
        const float4 v = reinterpret_cast<const float4*>(msg + (size_t)j * 16)[p];
        acc.x += v.x; acc.y += v.y; acc.z += v.z; acc.w += v.w;
        ++cnt;
        j = next[j];
    }

    acc.x += __shfl_xor(acc.x, 4); acc.y += __shfl_xor(acc.y, 4);
    acc.z += __shfl_xor(acc.z, 4); acc.w += __shfl_xor(acc.w, 4);
    cnt   += __shfl_xor(cnt, 4);
    acc.x += __shfl_xor(acc.x, 8); acc.y += __shfl_xor(acc.y, 8);
    acc.z += __shfl_xor(acc.z, 8); acc.w += __shfl_xor(acc.w, 8);
    cnt   += __shfl_xor(cnt, 8);

    const float inv = 1.0f / (float)(cnt > 1 ? cnt : 1);
    float4 m = s_bias4[p];
    m.x += acc.x * inv; m.y += acc.y * inv; m.z += acc.z * inv; m.w += acc.w * inv;

    {
        const float4* xp = reinterpret_cast<const float4*>(x) + (size_t)n * 4;
        float4 x0 = xp[0], x1 = xp[1], x2 = xp[2], x3 = xp[3];
        const float xs[IN_D] = { x0.x,x0.y,x0.z,x0.w, x1.x,x1.y,x1.z,x1.w,
                                 x2.x,x2.y,x2.z,x2.w, x3.x,x3.y,x3.z,x3.w };
        #pragma unroll
        for (int i = 0; i < IN_D; ++i) fma4(xs[i], s_root4[i * 4 + p], m);
    }

    if (c == 0)
        reinterpret_cast<float4*>(out + (size_t)n * 16)[p] = m;
}

extern "C" void kernel_launch(void* const* d_in, const int* in_sizes, int n_in,
                              void* d_out, int out_size, void* d_ws, size_t ws_size,
                              hipStream_t stream) {
    const float* x    = (const float*)d_in[0];
    const int*   ei   = (const int*)  d_in[1];
    const float* ea   = (const float*)d_in[2];
    const float* w1   = (const float*)d_in[3];
    const float* b1   = (const float*)d_in[4];
    const float* w2   = (const float*)d_in[5];
    const float* b2   = (const float*)d_in[6];
    const float* root = (const float*)d_in[7];
    const float* bias = (const float*)d_in[8];
    float* out = (float*)d_out;

    unsigned char* ws = (unsigned char*)d_ws;
    unsigned char* blob = ws;

    if (ws_size >= WS_NEED) {
        int*   deg  = (int*)(ws + WS_DEG);
        int*   off  = (int*)(ws + WS_OFF);
        int*   cur  = (int*)(ws + WS_CUR);
        int*   bsum = (int*)(ws + WS_BSUM);
        float* msg  = (float*)(ws + WS_MSG);
        hipMemsetAsync(deg, 0, N_NODES * sizeof(int), stream);
        setup_count_k<<<NBLK_E + 1, 256, 0, stream>>>(w1, b1, w2, b2, ei, blob, deg);
        scan1_k <<<NBLK_S, 256, 0, stream>>>(deg, bsum);
        scan23_k<<<NBLK_S, 256, 0, stream>>>(deg, bsum, off, cur);
        edge_k<0><<<NBLK_E, 256, 0, stream>>>(x, ei, ea, blob, cur, nullptr, msg);
        gather_csr<<<NBLK_G, 256, 0, stream>>>(x, root, bias, msg, off, out);
    } else {
        // 4-way linked list fallback (requires 0xAA ws poison for head4 sentinel)
        int*   head4 = (int*)(ws + BLOB_BYTES);       // N*4 ints
        int*   next  = head4 + N_NODES * 4;           // E ints
        float* msg   = (float*)(next + N_EDGES);      // E*16 f32
        setup_count_k<<<1, 256, 0, stream>>>(w1, b1, w2, b2, ei, blob, (int*)(ws + BLOB_BYTES));
        edge_k<1><<<NBLK_E, 256, 0, stream>>>(x, ei, ea, blob, head4, next, msg);
        gather_ll4  <<<NBLK_G, 256, 0, stream>>>(x, root, bias, msg, head4, next, out);
    }
}

// Round 4
// 184.334 us; speedup vs baseline: 1.7749x; 1.1357x over previous
//
#include <hip/hip_runtime.h>
#include <hip/hip_bf16.h>
#include <hip/hip_fp16.h>

// NNConv R17: fused aggregation via hardware f32 atomics. R16 post-mortem:
// edge_k improved to ~69us (blob L2-resident: FETCH 57.7 = ea+ei exactly), but
// ~140us lives OUTSIDE edge_k across 5 aux dispatches (setup_count/scan1/
// scan23/gather/memset) -- and the msg round-trip (51.2MB write x1.48 amp +
// 51.2MB read) exists only to compute a per-node sum. Replace all of it with
// direct scatter-add: edge_k does unsafeAtomicAdd (global_atomic_add_f32,
// device-scope, m20) of its C-fragment into sum[N][16] (3.2MB, L2-resident)
// + one int atomic for deg[dst]; node_k finishes out = sum/deg + x@root+bias.
// Pipeline: memset(3.4MB) -> setup(blob,1 blk) -> edge -> node. 4 dispatches,
// ws 3.4MB (was 51.8MB). 12.8M f32 atomics ~= 25-48us pipe time, overlapped
// with edge's 57.6MB fetch + MFMA; deletes ~55us of aux work + 3 launches.

#define N_NODES 50000
#define N_EDGES 800000
#define IN_D    16
#define OUT_D   16
#define HID_D   32
#define KTILES  17
#define NBLK_E  (N_EDGES / 256)            // 3125, exact
#define NBLK_N  (N_NODES * OUT_D / 256)    // 3125, exact
#define BLOB_BYTES 20480                   // 20 x 1KB chunks
#define BLOB_W1    17408                   // s_B image [0,17408)
#define BLOB_B1    19456                   // w1 [17408,19456), b1 [19456,19584)

// ws layout (byte offsets)
#define WS_SUM   20480                     // N*16 f32 = 3.2MB
#define WS_DEG   3220480                   // N ints = 200KB
#define WS_NEED  (3220480 + (size_t)N_NODES * 4)   // ~3.42MB

typedef __attribute__((ext_vector_type(8))) _Float16 hfrag8;
typedef __attribute__((ext_vector_type(4))) float f32x4;

__device__ __forceinline__ void fma4(float a, const float4 w, float4& m) {
    m.x = fmaf(a, w.x, m.x);
    m.y = fmaf(a, w.y, m.y);
    m.z = fmaf(a, w.z, m.z);
    m.w = fmaf(a, w.w, m.w);
}
__device__ __forceinline__ int clampn(int v) {
    return v < 0 ? 0 : (v >= N_NODES ? N_NODES - 1 : v);
}
__device__ __forceinline__ void gload_lds16(const void* g, void* l) {
    __builtin_amdgcn_global_load_lds(
        (const __attribute__((address_space(1))) unsigned int*)g,
        (__attribute__((address_space(3))) unsigned int*)l,
        16, 0, 0);
}

// ---------------- one-block setup: build {s_B f16 image, w1, b1} blob ----------------

__global__ __launch_bounds__(256) void setup_k(
    const float* __restrict__ w1,
    const float* __restrict__ b1,
    const float* __restrict__ w2,
    const float* __restrict__ b2,
    unsigned char* __restrict__ blob)
{
    const int t = threadIdx.x;
    __half* bp = reinterpret_cast<__half*>(blob);
    for (int r = t; r < KTILES * 32; r += 256) {
        const int tile = r >> 5, q = (r >> 3) & 3, j = r & 7;
        const int base = ((tile * 4 + q) * 16) * 8 + j;
        float vals[16];
        if (r < 512) {
            const float4* wr = reinterpret_cast<const float4*>(w2) + r * 4;
            float4 v0 = wr[0], v1 = wr[1], v2 = wr[2], v3 = wr[3];
            vals[0]=v0.x; vals[1]=v0.y; vals[2]=v0.z; vals[3]=v0.w;
            vals[4]=v1.x; vals[5]=v1.y; vals[6]=v1.z; vals[7]=v1.w;
            vals[8]=v2.x; vals[9]=v2.y; vals[10]=v2.z; vals[11]=v2.w;
            vals[12]=v3.x; vals[13]=v3.y; vals[14]=v3.z; vals[15]=v3.w;
        } else if (r < 528) {
            const float4* br = reinterpret_cast<const float4*>(b2) + (r - 512) * 4;
            float4 v0 = br[0], v1 = br[1], v2 = br[2], v3 = br[3];
            vals[0]=v0.x; vals[1]=v0.y; vals[2]=v0.z; vals[3]=v0.w;
            vals[4]=v1.x; vals[5]=v1.y; vals[6]=v1.z; vals[7]=v1.w;
            vals[8]=v2.x; vals[9]=v2.y; vals[10]=v2.z; vals[11]=v2.w;
            vals[12]=v3.x; vals[13]=v3.y; vals[14]=v3.z; vals[15]=v3.w;
        } else {
            #pragma unroll
            for (int o = 0; o < 16; ++o) vals[o] = 0.f;
        }
        #pragma unroll
        for (int o = 0; o < 16; ++o) bp[base + o * 8] = __float2half(vals[o]);
    }
    float* wf = reinterpret_cast<float*>(blob + BLOB_W1);
    wf[t]       = w1[t];
    wf[t + 256] = w1[t + 256];
    if (t < HID_D) reinterpret_cast<float*>(blob + BLOB_B1)[t] = b1[t];
}

// ---------------- edge kernel: MLP + MFMA + atomic scatter-add ----------------

__global__ __launch_bounds__(256) void edge_k(
    const float* __restrict__ x,
    const int*   __restrict__ ei,
    const float* __restrict__ ea,
    const unsigned char* __restrict__ gblob,
    int*   __restrict__ deg,
    float* __restrict__ sum)
{
    __shared__ alignas(16) unsigned char s_blob[BLOB_BYTES];   // 20 KB
    __shared__ alignas(16) __half s_h2[4 * 64 * 32];           // 16 KB: [wave][edge 64B row]

    const int t    = threadIdx.x;
    const int lane = t & 63;
    const int w    = t >> 6;
    const int e    = blockIdx.x * 256 + t;   // grid exact

    // ---- blob global->LDS: 20 x 1KB chunks across 4 waves
    #pragma unroll
    for (int j = 0; j < 5; ++j) {
        const int ch = w + 4 * j;            // 0..19
        gload_lds16(gblob + ch * 1024 + lane * 16, s_blob + ch * 1024);
    }

    const hfrag8* s_B  = reinterpret_cast<const hfrag8*>(s_blob);
    const float4* s_w1 = reinterpret_cast<const float4*>(s_blob + BLOB_W1);
    const float4* s_b1 = reinterpret_cast<const float4*>(s_blob + BLOB_B1);

    const int q   = lane >> 4;
    const int n   = lane & 15;
    const int qh  = q >> 1;
    const int i0q = (q & 1) * 8;

    // ---- indices; deg count; x/ea prefetch before the barrier ----
    const int src = clampn(ei[e]);
    const int dst = clampn(ei[N_EDGES + e]);
    atomicAdd(&deg[dst], 1);                 // retires during MLP

    float4 xpre[4][2];
    #pragma unroll
    for (int sub = 0; sub < 4; ++sub) {
        const int srcB = __shfl(src, sub * 16 + n, 64);
        const float4* xp = reinterpret_cast<const float4*>(x) + (size_t)srcB * 4 + (i0q >> 2);
        xpre[sub][0] = xp[0];
        xpre[sub][1] = xp[1];
    }
    float eav[IN_D];
    {
        const float4* eap = reinterpret_cast<const float4*>(ea) + (size_t)e * 4;
        float4 a0 = eap[0], a1 = eap[1], a2 = eap[2], a3 = eap[3];
        eav[0]=a0.x;  eav[1]=a0.y;  eav[2]=a0.z;  eav[3]=a0.w;
        eav[4]=a1.x;  eav[5]=a1.y;  eav[6]=a1.z;  eav[7]=a1.w;
        eav[8]=a2.x;  eav[9]=a2.y;  eav[10]=a2.z; eav[11]=a2.w;
        eav[12]=a3.x; eav[13]=a3.y; eav[14]=a3.z; eav[15]=a3.w;
    }

    __syncthreads();            // drains vmcnt (global_load_lds) + makes blob visible

    // ---- edge MLP h = relu(ea@w1+b1) -> packed 64B row, swizzled b128 writes ----
    {
        float4 hv[HID_D / 4];
        #pragma unroll
        for (int j = 0; j < HID_D / 4; ++j) hv[j] = s_b1[j];
        #pragma unroll
        for (int i = 0; i < IN_D; ++i) {
            const float xi = eav[i];
            #pragma unroll
            for (int j = 0; j < HID_D / 4; ++j) fma4(xi, s_w1[i * (HID_D / 4) + j], hv[j]);
        }
        // logical row layout: h[k] at slot (k&1)*16 + (k>>1)
        union { hfrag8 v[4]; __half h[32]; } hp;
        #pragma unroll
        for (int jj = 0; jj < 8; ++jj) {
            const int k0 = 4 * jj;
            hp.h[((k0 + 0) & 1) * 16 + ((k0 + 0) >> 1)] = __float2half(fmaxf(hv[jj].x, 0.f));
            hp.h[((k0 + 1) & 1) * 16 + ((k0 + 1) >> 1)] = __float2half(fmaxf(hv[jj].y, 0.f));
            hp.h[((k0 + 2) & 1) * 16 + ((k0 + 2) >> 1)] = __float2half(fmaxf(hv[jj].z, 0.f));
            hp.h[((k0 + 3) & 1) * 16 + ((k0 + 3) >> 1)] = __float2half(fmaxf(hv[jj].w, 0.f));
        }
        hfrag8* rowv = reinterpret_cast<hfrag8*>(s_h2 + (size_t)w * 2048 + lane * 32);
        const int swl = (lane >> 1) & 3;          // 16B-chunk XOR swizzle
        rowv[0 ^ swl] = hp.v[0];
        rowv[1 ^ swl] = hp.v[1];
        rowv[2 ^ swl] = hp.v[2];
        rowv[3 ^ swl] = hp.v[3];
    }
    asm volatile("s_waitcnt lgkmcnt(0)" ::: "memory");
    __builtin_amdgcn_wave_barrier();

    // ---- MFMA phase + atomic scatter-add epilogue ----
    const __half* hbase = s_h2 + (size_t)w * 2048;
    #pragma unroll
    for (int sub = 0; sub < 4; ++sub) {
        const int posW = sub * 16 + n;
        __half2 xh[4];
        {
            float4 xa = xpre[sub][0], xb = xpre[sub][1];
            xh[0] = __float22half2_rn(make_float2(xa.x, xa.y));
            xh[1] = __float22half2_rn(make_float2(xa.z, xa.w));
            xh[2] = __float22half2_rn(make_float2(xb.x, xb.y));
            xh[3] = __float22half2_rn(make_float2(xb.z, xb.w));
        }
        union { hfrag8 v; __half h[8]; } hA, hB;   // tiles 0-7 / 8-15 for this qh
        {
            const hfrag8* rowv = reinterpret_cast<const hfrag8*>(hbase + posW * 32);
            const int swr = (posW >> 1) & 3;
            hA.v = rowv[(2 * qh + 0) ^ swr];
            hB.v = rowv[(2 * qh + 1) ^ swr];
        }
        f32x4 acc = {0.f, 0.f, 0.f, 0.f};
        #pragma unroll
        for (int tile = 0; tile < 16; ++tile) {
            const __half hs = (tile < 8) ? hA.h[tile] : hB.h[tile - 8];   // h[2*tile+qh]
            const __half2 hh = __half2half2(hs);
            union { hfrag8 v; __half2 h[4]; } a;
            a.h[0] = __hmul2(hh, xh[0]);
            a.h[1] = __hmul2(hh, xh[1]);
            a.h[2] = __hmul2(hh, xh[2]);
            a.h[3] = __hmul2(hh, xh[3]);
            acc = __builtin_amdgcn_mfma_f32_16x16x32_f16(a.v, s_B[tile * 64 + lane], acc, 0, 0, 0);
        }
        {   // b2 tile: A = x (qh==0) / 0 (qh==1)
            union { hfrag8 v; __half2 h[4]; } a;
            if (qh == 0) { a.h[0]=xh[0]; a.h[1]=xh[1]; a.h[2]=xh[2]; a.h[3]=xh[3]; }
            else { hfrag8 z = {0,0,0,0,0,0,0,0}; a.v = z; }
            acc = __builtin_amdgcn_mfma_f32_16x16x32_f16(a.v, s_B[16 * 64 + lane], acc, 0, 0, 0);
        }
        // hardware f32 atomic add into the owning node's sum row (dst shuffled
        // from the edge's owner lane; 16 lanes cover the 16 output columns)
        #pragma unroll
        for (int r = 0; r < 4; ++r) {
            const int dstB = __shfl(dst, sub * 16 + q * 4 + r, 64);
            unsafeAtomicAdd(&sum[(size_t)dstB * 16 + n], acc[r]);
        }
    }
}

// ---------------- node kernel: out = sum/deg + x@root + bias ----------------

__global__ __launch_bounds__(256) void node_k(
    const float* __restrict__ x,
    const float* __restrict__ root,
    const float* __restrict__ bias,
    const float* __restrict__ sum,
    const int*   __restrict__ deg,
    float* __restrict__ out)
{
    __shared__ float s_root[IN_D * OUT_D];
    __shared__ float s_bias[OUT_D];
    const int t = threadIdx.x;
    s_root[t] = root[t];
    if (t < OUT_D) s_bias[t] = bias[t];
    __syncthreads();

    const int g = blockIdx.x * 256 + t;      // grid exact: 3125*256 = 50000*16
    const int n = g >> 4;
    const int o = g & 15;

    const float s = sum[g];
    const int   d = deg[n];
    float mv = s * (1.0f / (float)(d > 1 ? d : 1)) + s_bias[o];

    float xs[IN_D];
    {
        const float4* xp = reinterpret_cast<const float4*>(x) + (size_t)n * 4;
        float4 b0 = xp[0], b1v = xp[1], b2v = xp[2], b3 = xp[3];
        xs[0]=b0.x;  xs[1]=b0.y;  xs[2]=b0.z;  xs[3]=b0.w;
        xs[4]=b1v.x; xs[5]=b1v.y; xs[6]=b1v.z; xs[7]=b1v.w;
        xs[8]=b2v.x; xs[9]=b2v.y; xs[10]=b2v.z; xs[11]=b2v.w;
        xs[12]=b3.x; xs[13]=b3.y; xs[14]=b3.z; xs[15]=b3.w;
    }
    #pragma unroll
    for (int i = 0; i < IN_D; ++i)
        mv = fmaf(xs[i], s_root[i * OUT_D + o], mv);

    out[g] = mv;
}

extern "C" void kernel_launch(void* const* d_in, const int* in_sizes, int n_in,
                              void* d_out, int out_size, void* d_ws, size_t ws_size,
                              hipStream_t stream) {
    const float* x    = (const float*)d_in[0];
    const int*   ei   = (const int*)  d_in[1];
    const float* ea   = (const float*)d_in[2];
    const float* w1   = (const float*)d_in[3];
    const float* b1   = (const float*)d_in[4];
    const float* w2   = (const float*)d_in[5];
    const float* b2   = (const float*)d_in[6];
    const float* root = (const float*)d_in[7];
    const float* bias = (const float*)d_in[8];
    float* out = (float*)d_out;

    unsigned char* ws   = (unsigned char*)d_ws;
    unsigned char* blob = ws;
    float* sum = (float*)(ws + WS_SUM);      // N*16 f32, 3.2MB (L2-resident)
    int*   deg = (int*)(ws + WS_DEG);        // N ints

    // zero sum+deg in one contiguous memset (3.4MB)
    hipMemsetAsync(ws + WS_SUM, 0, (size_t)N_NODES * 16 * 4 + (size_t)N_NODES * 4, stream);
    setup_k<<<1, 256, 0, stream>>>(w1, b1, w2, b2, blob);
    edge_k<<<NBLK_E, 256, 0, stream>>>(x, ei, ea, blob, deg, sum);
    node_k<<<NBLK_N, 256, 0, stream>>>(x, root, bias, sum, deg, out);
}

// Round 5
// 184.002 us; speedup vs baseline: 1.7781x; 1.0018x over previous
//
#include <hip/hip_runtime.h>
#include <hip/hip_bf16.h>
#include <hip/hip_fp16.h>

// NNConv R18: occupancy attack on edge_k. R17 post-mortem: fused atomics won
// net (-25us total) but WRITE_SIZE=74.9MB proved device-scope f32 atomics
// resolve at the MEMORY SIDE (per-XCD L2s non-coherent) -> +16us in edge_k.
// edge_k is still stall-bound: Mfma 6.4 / VALU 26 / HBM 19 / Occ 34% -- all
// pipes idle, 16 waves/CU can't hide the chain. LDS was the cap (36.9KB -> 4
// blk/CU). Fix: s_h2 is per-wave scratch and each MFMA sub only needs 16 rows
// produced by lanes sub*16..+15 -> time-multiplex ONE 1KB/wave phase buffer:
// phase s = {16 writers store, wave_barrier, all read 2xb128, MFMA, atomics}.
// LDS 36.9->24KB => 6 blk/CU = 24 waves/CU (75%). x-prefetch becomes 1-ahead
// pipeline (2 float4 in flight, was 8) so VGPR stays <=80 (launch_bounds 256,6).
// Epilogue/setup/node unchanged to isolate the occupancy lever.
// Predicted: Occ 34->60-75, edge 85->~65us, total 184->~165us. If Occ rises
// but dur >=78: atomic pipe is binding -> next round attacks epilogue.

#define N_NODES 50000
#define N_EDGES 800000
#define IN_D    16
#define OUT_D   16
#define HID_D   32
#define KTILES  17
#define NBLK_E  (N_EDGES / 256)            // 3125, exact
#define NBLK_N  (N_NODES * OUT_D / 256)    // 3125, exact
#define BLOB_BYTES 20480                   // 20 x 1KB chunks
#define BLOB_W1    17408                   // s_B image [0,17408)
#define BLOB_B1    19456                   // w1 [17408,19456), b1 [19456,19584)

// ws layout (byte offsets)
#define WS_SUM   20480                     // N*16 f32 = 3.2MB
#define WS_DEG   3220480                   // N ints = 200KB
#define WS_NEED  (3220480 + (size_t)N_NODES * 4)   // ~3.42MB

typedef __attribute__((ext_vector_type(8))) _Float16 hfrag8;
typedef __attribute__((ext_vector_type(4))) float f32x4;

__device__ __forceinline__ void fma4(float a, const float4 w, float4& m) {
    m.x = fmaf(a, w.x, m.x);
    m.y = fmaf(a, w.y, m.y);
    m.z = fmaf(a, w.z, m.z);
    m.w = fmaf(a, w.w, m.w);
}
__device__ __forceinline__ int clampn(int v) {
    return v < 0 ? 0 : (v >= N_NODES ? N_NODES - 1 : v);
}
__device__ __forceinline__ void gload_lds16(const void* g, void* l) {
    __builtin_amdgcn_global_load_lds(
        (const __attribute__((address_space(1))) unsigned int*)g,
        (__attribute__((address_space(3))) unsigned int*)l,
        16, 0, 0);
}

// ---------------- one-block setup: build {s_B f16 image, w1, b1} blob ----------------

__global__ __launch_bounds__(256) void setup_k(
    const float* __restrict__ w1,
    const float* __restrict__ b1,
    const float* __restrict__ w2,
    const float* __restrict__ b2,
    unsigned char* __restrict__ blob)
{
    const int t = threadIdx.x;
    __half* bp = reinterpret_cast<__half*>(blob);
    for (int r = t; r < KTILES * 32; r += 256) {
        const int tile = r >> 5, q = (r >> 3) & 3, j = r & 7;
        const int base = ((tile * 4 + q) * 16) * 8 + j;
        float vals[16];
        if (r < 512) {
            const float4* wr = reinterpret_cast<const float4*>(w2) + r * 4;
            float4 v0 = wr[0], v1 = wr[1], v2 = wr[2], v3 = wr[3];
            vals[0]=v0.x; vals[1]=v0.y; vals[2]=v0.z; vals[3]=v0.w;
            vals[4]=v1.x; vals[5]=v1.y; vals[6]=v1.z; vals[7]=v1.w;
            vals[8]=v2.x; vals[9]=v2.y; vals[10]=v2.z; vals[11]=v2.w;
            vals[12]=v3.x; vals[13]=v3.y; vals[14]=v3.z; vals[15]=v3.w;
        } else if (r < 528) {
            const float4* br = reinterpret_cast<const float4*>(b2) + (r - 512) * 4;
            float4 v0 = br[0], v1 = br[1], v2 = br[2], v3 = br[3];
            vals[0]=v0.x; vals[1]=v0.y; vals[2]=v0.z; vals[3]=v0.w;
            vals[4]=v1.x; vals[5]=v1.y; vals[6]=v1.z; vals[7]=v1.w;
            vals[8]=v2.x; vals[9]=v2.y; vals[10]=v2.z; vals[11]=v2.w;
            vals[12]=v3.x; vals[13]=v3.y; vals[14]=v3.z; vals[15]=v3.w;
        } else {
            #pragma unroll
            for (int o = 0; o < 16; ++o) vals[o] = 0.f;
        }
        #pragma unroll
        for (int o = 0; o < 16; ++o) bp[base + o * 8] = __float2half(vals[o]);
    }
    float* wf = reinterpret_cast<float*>(blob + BLOB_W1);
    wf[t]       = w1[t];
    wf[t + 256] = w1[t + 256];
    if (t < HID_D) reinterpret_cast<float*>(blob + BLOB_B1)[t] = b1[t];
}

// ---------------- edge kernel: MLP + phased MFMA + atomic scatter-add ----------------

__global__ __launch_bounds__(256, 6) void edge_k(
    const float* __restrict__ x,
    const int*   __restrict__ ei,
    const float* __restrict__ ea,
    const unsigned char* __restrict__ gblob,
    int*   __restrict__ deg,
    float* __restrict__ sum)
{
    __shared__ alignas(16) unsigned char s_blob[BLOB_BYTES];   // 20 KB
    __shared__ alignas(16) __half s_h2[4 * 16 * 32];           // 4 KB: per-wave 16-row phase buf

    const int t    = threadIdx.x;
    const int lane = t & 63;
    const int w    = t >> 6;
    const int e    = blockIdx.x * 256 + t;   // grid exact

    // ---- blob global->LDS: 20 x 1KB chunks across 4 waves
    #pragma unroll
    for (int j = 0; j < 5; ++j) {
        const int ch = w + 4 * j;            // 0..19
        gload_lds16(gblob + ch * 1024 + lane * 16, s_blob + ch * 1024);
    }

    const hfrag8* s_B  = reinterpret_cast<const hfrag8*>(s_blob);
    const float4* s_w1 = reinterpret_cast<const float4*>(s_blob + BLOB_W1);
    const float4* s_b1 = reinterpret_cast<const float4*>(s_blob + BLOB_B1);

    const int q   = lane >> 4;
    const int n   = lane & 15;
    const int qh  = q >> 1;
    const int i0q = (q & 1) * 8;
    const int swz = (lane >> 1) & 3;         // bits 1-2 of lane == bits 1-2 of row index

    // ---- indices; deg count; ea + sub-0 x row prefetch before the barrier ----
    const int src = clampn(ei[e]);
    const int dst = clampn(ei[N_EDGES + e]);
    atomicAdd(&deg[dst], 1);                 // retires during MLP

    float eav[IN_D];
    {
        const float4* eap = reinterpret_cast<const float4*>(ea) + (size_t)e * 4;
        float4 a0 = eap[0], a1 = eap[1], a2 = eap[2], a3 = eap[3];
        eav[0]=a0.x;  eav[1]=a0.y;  eav[2]=a0.z;  eav[3]=a0.w;
        eav[4]=a1.x;  eav[5]=a1.y;  eav[6]=a1.z;  eav[7]=a1.w;
        eav[8]=a2.x;  eav[9]=a2.y;  eav[10]=a2.z; eav[11]=a2.w;
        eav[12]=a3.x; eav[13]=a3.y; eav[14]=a3.z; eav[15]=a3.w;
    }
    float4 xn0, xn1;                         // 1-ahead x pipeline (2 float4 in flight)
    {
        const int srcB = __shfl(src, n, 64); // sub 0
        const float4* xp = reinterpret_cast<const float4*>(x) + (size_t)srcB * 4 + (i0q >> 2);
        xn0 = xp[0]; xn1 = xp[1];
    }

    __syncthreads();            // drains vmcnt (global_load_lds) + makes blob visible

    // ---- edge MLP h = relu(ea@w1+b1) -> hp registers (64B row image) ----
    union { hfrag8 v[4]; __half h[32]; } hp;
    {
        float4 hv[HID_D / 4];
        #pragma unroll
        for (int j = 0; j < HID_D / 4; ++j) hv[j] = s_b1[j];
        #pragma unroll
        for (int i = 0; i < IN_D; ++i) {
            const float xi = eav[i];
            #pragma unroll
            for (int j = 0; j < HID_D / 4; ++j) fma4(xi, s_w1[i * (HID_D / 4) + j], hv[j]);
        }
        // logical row layout: h[k] at slot (k&1)*16 + (k>>1)
        #pragma unroll
        for (int jj = 0; jj < 8; ++jj) {
            const int k0 = 4 * jj;
            hp.h[((k0 + 0) & 1) * 16 + ((k0 + 0) >> 1)] = __float2half(fmaxf(hv[jj].x, 0.f));
            hp.h[((k0 + 1) & 1) * 16 + ((k0 + 1) >> 1)] = __float2half(fmaxf(hv[jj].y, 0.f));
            hp.h[((k0 + 2) & 1) * 16 + ((k0 + 2) >> 1)] = __float2half(fmaxf(hv[jj].z, 0.f));
            hp.h[((k0 + 3) & 1) * 16 + ((k0 + 3) >> 1)] = __float2half(fmaxf(hv[jj].w, 0.f));
        }
    }

    __half* hwav = reinterpret_cast<__half*>(s_h2) + w * 512;   // 1KB per wave

    // ---- 4 phases: {16 writers store row, wave_barrier, read 2xb128, MFMA, atomics} ----
    #pragma unroll
    for (int sub = 0; sub < 4; ++sub) {
        const float4 xa = xn0, xb = xn1;
        if (sub < 3) {                       // issue next phase's x row (latency hidden)
            const int srcB = __shfl(src, (sub + 1) * 16 + n, 64);
            const float4* xp = reinterpret_cast<const float4*>(x) + (size_t)srcB * 4 + (i0q >> 2);
            xn0 = xp[0]; xn1 = xp[1];
        }
        // WAR guard: previous phase's reads complete before overwrite (in-wave
        // DS ops are in-order; fences stop compiler motion)
        asm volatile("s_waitcnt lgkmcnt(0)" ::: "memory");
        __builtin_amdgcn_wave_barrier();
        if ((lane >> 4) == sub) {
            hfrag8* rowv = reinterpret_cast<hfrag8*>(hwav + (lane & 15) * 32);
            rowv[0 ^ swz] = hp.v[0];
            rowv[1 ^ swz] = hp.v[1];
            rowv[2 ^ swz] = hp.v[2];
            rowv[3 ^ swz] = hp.v[3];
        }
        asm volatile("s_waitcnt lgkmcnt(0)" ::: "memory");
        __builtin_amdgcn_wave_barrier();

        union { hfrag8 v; __half h[8]; } hA, hB;   // tiles 0-7 / 8-15 for this qh
        {
            const hfrag8* rowv = reinterpret_cast<const hfrag8*>(hwav + n * 32);
            hA.v = rowv[(2 * qh + 0) ^ swz];
            hB.v = rowv[(2 * qh + 1) ^ swz];
        }
        __half2 xh[4];
        xh[0] = __float22half2_rn(make_float2(xa.x, xa.y));
        xh[1] = __float22half2_rn(make_float2(xa.z, xa.w));
        xh[2] = __float22half2_rn(make_float2(xb.x, xb.y));
        xh[3] = __float22half2_rn(make_float2(xb.z, xb.w));

        f32x4 acc = {0.f, 0.f, 0.f, 0.f};
        #pragma unroll
        for (int tile = 0; tile < 16; ++tile) {
            const __half hs = (tile < 8) ? hA.h[tile] : hB.h[tile - 8];   // h[2*tile+qh]
            const __half2 hh = __half2half2(hs);
            union { hfrag8 v; __half2 h[4]; } a;
            a.h[0] = __hmul2(hh, xh[0]);
            a.h[1] = __hmul2(hh, xh[1]);
            a.h[2] = __hmul2(hh, xh[2]);
            a.h[3] = __hmul2(hh, xh[3]);
            acc = __builtin_amdgcn_mfma_f32_16x16x32_f16(a.v, s_B[tile * 64 + lane], acc, 0, 0, 0);
        }
        {   // b2 tile: A = x (qh==0) / 0 (qh==1)
            union { hfrag8 v; __half2 h[4]; } a;
            if (qh == 0) { a.h[0]=xh[0]; a.h[1]=xh[1]; a.h[2]=xh[2]; a.h[3]=xh[3]; }
            else { hfrag8 z = {0,0,0,0,0,0,0,0}; a.v = z; }
            acc = __builtin_amdgcn_mfma_f32_16x16x32_f16(a.v, s_B[16 * 64 + lane], acc, 0, 0, 0);
        }
        // hardware f32 atomic add into the owning node's sum row
        #pragma unroll
        for (int r = 0; r < 4; ++r) {
            const int dstB = __shfl(dst, sub * 16 + q * 4 + r, 64);
            unsafeAtomicAdd(&sum[(size_t)dstB * 16 + n], acc[r]);
        }
    }
}

// ---------------- node kernel: out = sum/deg + x@root + bias ----------------

__global__ __launch_bounds__(256) void node_k(
    const float* __restrict__ x,
    const float* __restrict__ root,
    const float* __restrict__ bias,
    const float* __restrict__ sum,
    const int*   __restrict__ deg,
    float* __restrict__ out)
{
    __shared__ float s_root[IN_D * OUT_D];
    __shared__ float s_bias[OUT_D];
    const int t = threadIdx.x;
    s_root[t] = root[t];
    if (t < OUT_D) s_bias[t] = bias[t];
    __syncthreads();

    const int g = blockIdx.x * 256 + t;      // grid exact: 3125*256 = 50000*16
    const int n = g >> 4;
    const int o = g & 15;

    const float s = sum[g];
    const int   d = deg[n];
    float mv = s * (1.0f / (float)(d > 1 ? d : 1)) + s_bias[o];

    float xs[IN_D];
    {
        const float4* xp = reinterpret_cast<const float4*>(x) + (size_t)n * 4;
        float4 b0 = xp[0], b1v = xp[1], b2v = xp[2], b3 = xp[3];
        xs[0]=b0.x;  xs[1]=b0.y;  xs[2]=b0.z;  xs[3]=b0.w;
        xs[4]=b1v.x; xs[5]=b1v.y; xs[6]=b1v.z; xs[7]=b1v.w;
        xs[8]=b2v.x; xs[9]=b2v.y; xs[10]=b2v.z; xs[11]=b2v.w;
        xs[12]=b3.x; xs[13]=b3.y; xs[14]=b3.z; xs[15]=b3.w;
    }
    #pragma unroll
    for (int i = 0; i < IN_D; ++i)
        mv = fmaf(xs[i], s_root[i * OUT_D + o], mv);

    out[g] = mv;
}

extern "C" void kernel_launch(void* const* d_in, const int* in_sizes, int n_in,
                              void* d_out, int out_size, void* d_ws, size_t ws_size,
                              hipStream_t stream) {
    const float* x    = (const float*)d_in[0];
    const int*   ei   = (const int*)  d_in[1];
    const float* ea   = (const float*)d_in[2];
    const float* w1   = (const float*)d_in[3];
    const float* b1   = (const float*)d_in[4];
    const float* w2   = (const float*)d_in[5];
    const float* b2   = (const float*)d_in[6];
    const float* root = (const float*)d_in[7];
    const float* bias = (const float*)d_in[8];
    float* out = (float*)d_out;

    unsigned char* ws   = (unsigned char*)d_ws;
    unsigned char* blob = ws;
    float* sum = (float*)(ws + WS_SUM);      // N*16 f32, 3.2MB
    int*   deg = (int*)(ws + WS_DEG);        // N ints

    // zero sum+deg in one contiguous memset (3.4MB)
    hipMemsetAsync(ws + WS_SUM, 0, (size_t)N_NODES * 16 * 4 + (size_t)N_NODES * 4, stream);
    setup_k<<<1, 256, 0, stream>>>(w1, b1, w2, b2, blob);
    edge_k<<<NBLK_E, 256, 0, stream>>>(x, ei, ea, blob, deg, sum);
    node_k<<<NBLK_N, 256, 0, stream>>>(x, root, bias, sum, deg, out);
}